// Round 9
// baseline (213.120 us; speedup 1.0000x reference)
//
#include <hip/hip_runtime.h>
#include <hip/hip_bf16.h>
#include <stdint.h>

#define EMB 1024
#define SEQ 2048
#define NB 2
#define NH 16
#define HD 64
#define QKVN 3072
#define BSROWS (NB*SEQ)   // 4096

typedef __attribute__((ext_vector_type(8))) short short8;
typedef __attribute__((ext_vector_type(4))) float f32x4;
typedef __attribute__((ext_vector_type(4))) unsigned short u16x4;

__device__ __forceinline__ float bf2f(unsigned short u){
  union{uint32_t i; float f;} x; x.i = ((uint32_t)u)<<16; return x.f;
}
__device__ __forceinline__ unsigned short f2bf(float f){
  union{float f; uint32_t i;} x; x.f = f;
  return (unsigned short)((x.i + 0x7FFFu + ((x.i>>16)&1u))>>16);
}

__device__ __forceinline__ void gload_lds16(const void* g, void* l){
  __builtin_amdgcn_global_load_lds((const __attribute__((address_space(1))) void*)g,
                                   (__attribute__((address_space(3))) void*)l, 16, 0, 0);
}

// ---------------- prep: RMSNorm rows + fp32->bf16 weight convert, one launch -------
__global__ __launch_bounds__(256) void k_prep(const float* __restrict__ x,
                                              const float* __restrict__ w,
                                              unsigned short* __restrict__ normed,
                                              const float* __restrict__ qkvw,
                                              const float* __restrict__ outw,
                                              unsigned short* __restrict__ qkvWb,
                                              unsigned short* __restrict__ outWb){
  int bid = blockIdx.x;
  if(bid < BSROWS){
    int row = bid;
    const float4* xr = (const float4*)(x + (size_t)row*EMB);
    float4 v = xr[threadIdx.x];
    float ss = v.x*v.x + v.y*v.y + v.z*v.z + v.w*v.w;
    #pragma unroll
    for(int m=1;m<64;m<<=1) ss += __shfl_xor(ss, m, 64);
    __shared__ float red[4];
    if((threadIdx.x & 63)==0) red[threadIdx.x>>6] = ss;
    __syncthreads();
    float tot = red[0]+red[1]+red[2]+red[3];
    float rinv = rsqrtf(tot*(1.0f/EMB) + 1.1920929e-07f);
    float4 wv = ((const float4*)w)[threadIdx.x];
    u16x4 o;
    o.x = f2bf(v.x*wv.x*rinv); o.y = f2bf(v.y*wv.y*rinv);
    o.z = f2bf(v.z*wv.z*rinv); o.w = f2bf(v.w*wv.w*rinv);
    *(u16x4*)(normed + (size_t)row*EMB + threadIdx.x*4) = o;
  } else {
    const int na4 = QKVN*EMB/4, nb4 = EMB*EMB/4;
    int i = (bid - BSROWS)*256 + threadIdx.x;
    const float* src; unsigned short* dst; int idx;
    if(i < na4){ src = qkvw; dst = qkvWb; idx = i; }
    else { idx = i - na4; if(idx >= nb4) return; src = outw; dst = outWb; }
    float4 v = ((const float4*)src)[idx];
    u16x4 o;
    o.x = f2bf(v.x); o.y = f2bf(v.y); o.z = f2bf(v.z); o.w = f2bf(v.w);
    ((u16x4*)dst)[idx] = o;
  }
}

// ---------------- GEMM: C[M,N] = A[M,K](bf16) @ W[N,K](bf16)^T ---------------------
// MODE 1: fp32 (acc + resid) -> Cf                         [out-proj]
// MODE 2: reversed operands (n on regs), RoPE epilogue -> qb/kb  [qkv cols 0..2047]
// MODE 3: normal operands (m on regs), V transpose+perm -> vtb   [qkv cols 2048..3071]
template<int MODE>
__global__ __launch_bounds__(256) void k_gemm(const unsigned short* __restrict__ A,
                                              const unsigned short* __restrict__ W,
                                              float* __restrict__ Cf,
                                              const float* __restrict__ resid,
                                              const float* __restrict__ cosb,
                                              const float* __restrict__ sinb,
                                              unsigned short* __restrict__ qb,
                                              unsigned short* __restrict__ kb,
                                              unsigned short* __restrict__ vtb,
                                              int M, int N, int K, int n_off){
  __shared__ unsigned short As[128*32];
  __shared__ unsigned short Bs[128*32];
  const int tid = threadIdx.x;
  const int l  = tid & 63;
  const int wid = tid >> 6;
  const int lr = l & 15, lh = l >> 4;
  const int m0 = blockIdx.y * 128, n0 = blockIdx.x * 128 + n_off;
  const int wr = wid >> 1, wc = wid & 1;   // 2x2 waves of 64x64

  f32x4 acc[4][4] = {};

  const int nk = K >> 5;
  for(int kt=0; kt<nk; kt++){
    const int k0 = kt*32;
    #pragma unroll
    for(int j=0;j<2;j++){
      int c = j*256 + tid;            // chunk 0..511, 16B each
      int r = c >> 2, kc = (c & 3)*8;
      gload_lds16(A + (size_t)(m0+r)*K + k0 + kc, &As[(size_t)(j*256 + wid*64)*8]);
      gload_lds16(W + (size_t)(n0+r)*K + k0 + kc, &Bs[(size_t)(j*256 + wid*64)*8]);
    }
    __syncthreads();
    short8 af[4], bfr[4];
    #pragma unroll
    for(int i=0;i<4;i++){
      af[i]  = *(const short8*)&As[(size_t)((wr*64 + i*16 + lr)*32 + lh*8)];
      bfr[i] = *(const short8*)&Bs[(size_t)((wc*64 + i*16 + lr)*32 + lh*8)];
    }
    #pragma unroll
    for(int i=0;i<4;i++)
      #pragma unroll
      for(int jn=0;jn<4;jn++){
        if(MODE==2)
          acc[i][jn] = __builtin_amdgcn_mfma_f32_16x16x32_bf16(bfr[jn], af[i], acc[i][jn], 0,0,0);
        else
          acc[i][jn] = __builtin_amdgcn_mfma_f32_16x16x32_bf16(af[i], bfr[jn], acc[i][jn], 0,0,0);
      }
    __syncthreads();
  }

  const int rbase = m0 + wr*64, cbase = n0 + wc*64;

  if(MODE==1){
    #pragma unroll
    for(int i=0;i<4;i++){
      #pragma unroll
      for(int jn=0;jn<4;jn++){
        int rr = rbase + i*16 + lh*4;
        int cc = cbase + jn*16 + lr;
        #pragma unroll
        for(int t=0;t<4;t++)
          Cf[(size_t)(rr+t)*N + cc] = acc[i][jn][t] + resid[(size_t)(rr+t)*N + cc];
      }
    }
  } else if(MODE==2){
    // reversed: lane holds m = rbase+i*16+lr; regs span n = cbase+jn*16+lh*4+t
    const int part = cbase >> 10;              // 0=q, 1=k
    const int h = (cbase >> 6) & 15;
    const float qs = part ? 1.0f : 0.125f*1.4426950408889634f;
    unsigned short* dst = part ? kb : qb;
    #pragma unroll
    for(int i=0;i<4;i++){
      int s = rbase + i*16 + lr;
      int b = s >> 11, sl = s & 2047;
      unsigned short* rowp = dst + ((size_t)((b*NH + h)*SEQ + sl))*HD;
      const float* cp = cosb + (size_t)sl*HD;
      const float* sp = sinb + (size_t)sl*HD;
      #pragma unroll
      for(int jn=0;jn<4;jn++){
        int d0 = jn*16 + lh*4;
        f32x4 cs = *(const f32x4*)(cp + d0);
        f32x4 sn = *(const f32x4*)(sp + d0);
        u16x4 ov;
        #pragma unroll
        for(int t=0;t<4;t++)
          ov[t] = f2bf((cs[t]*acc[i][jn][t] + sn[t]*acc[i][jn^2][t])*qs);
        *(u16x4*)(rowp + d0) = ov;
      }
    }
  } else {
    // MODE 3: lane holds d = jn*16+lr; regs span s = rbase+i*16+lh*4+t.
    // Store into Vt[b,h,d, s-permuted] (32-block chunk perm pos = 2*lh + (i&1)).
    const int h = (cbase >> 6) & 15;
    const int b = m0 >> 11;
    const int rb = rbase & 2047;
    #pragma unroll
    for(int i=0;i<4;i++){
      int sl = rb + (i & ~1)*16 + (lh*2 + (i&1))*4;
      #pragma unroll
      for(int jn=0;jn<4;jn++){
        int d = jn*16 + lr;
        u16x4 ov;
        #pragma unroll
        for(int t=0;t<4;t++) ov[t] = f2bf(acc[i][jn][t]);
        *(u16x4*)(vtb + ((size_t)((b*NH + h)*HD + d))*SEQ + sl) = ov;
      }
    }
  }
}

// ---------------- Flash attention: LDS-staged KV64, lean softmax -------------------
__global__ __launch_bounds__(256, 4) void k_attn(const unsigned short* __restrict__ Q,
                                                 const unsigned short* __restrict__ K,
                                                 const unsigned short* __restrict__ Vt,
                                                 unsigned short* __restrict__ O){
  __shared__ unsigned short Ks[2][64*64];
  __shared__ unsigned short Vs[2][64*64];
  const int tid = threadIdx.x;
  const int l = tid & 63, wid = tid >> 6;
  const int lr = l & 15, lh = l >> 4;
  const int id = blockIdx.x;
  const int slot = id >> 3;
  const int bh  = (id & 7)*4 + (slot & 3);    // XCD-local bh group (K+V = 2MB/XCD L2)
  const int qblk = 31 - (slot >> 2);          // heavy q-blocks dispatch first
  const int q0 = qblk*64 + wid*16;
  const unsigned short* Qp = Q + ((size_t)bh*SEQ + q0)*HD;
  const unsigned short* Kp = K + (size_t)bh*SEQ*HD;
  const unsigned short* Vp = Vt + (size_t)bh*HD*SEQ;

  short8 qf0 = *(const short8*)&Qp[lr*HD + lh*8];
  short8 qf1 = *(const short8*)&Qp[lr*HD + 32 + lh*8];

  f32x4 o[4] = {};
  float m_ = -__builtin_inff();
  float ls = 0.f;                 // per-lane; reduced once at the end
  const int qg = q0 + lr;
  const int swz = lr & 7;
  const int T = qblk + 1;

  #define STAGE(t_, b_) { \
    const int kv0s = (t_)*64; \
    _Pragma("unroll") \
    for(int j=0;j<2;j++){ \
      int s = j*256 + tid; \
      int sb = j*256 + wid*64; \
      int r = s >> 3, c = s & 7; \
      gload_lds16(Kp + (size_t)(kv0s + r)*HD + ((c ^ (r & 7))*8), &Ks[b_][sb*8]); \
      gload_lds16(Vp + (size_t)r*SEQ + kv0s + ((c ^ (r & 7))*8), &Vs[b_][sb*8]); \
    } }

  auto body = [&](int kv0, const unsigned short* Kb, const unsigned short* Vb,
                  bool masked){
    f32x4 s4[4] = {};
    #pragma unroll
    for(int i=0;i<4;i++){
      int row = i*16 + lr;
      short8 ka = *(const short8*)&Kb[(row*8 + (lh ^ swz))*8];
      short8 kc = *(const short8*)&Kb[(row*8 + ((4+lh) ^ swz))*8];
      s4[i] = __builtin_amdgcn_mfma_f32_16x16x32_bf16(ka, qf0, s4[i], 0,0,0);
      s4[i] = __builtin_amdgcn_mfma_f32_16x16x32_bf16(kc, qf1, s4[i], 0,0,0);
    }
    float v[16];
    #pragma unroll
    for(int i=0;i<4;i++)
      #pragma unroll
      for(int j=0;j<4;j++){
        float val = s4[i][j];
        if(masked){
          int kvg = kv0 + i*16 + lh*4 + j;
          val = (kvg <= qg) ? val : -__builtin_inff();
        }
        v[i*4+j] = val;
      }
    float pm = v[0];
    #pragma unroll
    for(int j=1;j<16;j++) pm = fmaxf(pm, v[j]);
    if(__any(pm > m_ + 11.544f)){
      float mx = fmaxf(pm, __shfl_xor(pm, 16, 64));
      mx = fmaxf(mx, __shfl_xor(mx, 32, 64));
      float mn = fmaxf(m_, mx);
      float cr = __builtin_amdgcn_exp2f(m_ - mn);
      m_ = mn;
      ls *= cr;
      #pragma unroll
      for(int f=0; f<4; f++) o[f] *= cr;
    }
    float p[16], rs = 0.f;
    #pragma unroll
    for(int j=0;j<16;j++){ p[j] = __builtin_amdgcn_exp2f(v[j] - m_); rs += p[j]; }
    ls += rs;

    union { short8 s8; uint32_t u[4]; } P0, P1;
    #pragma unroll
    for(int j=0;j<4;j++){
      asm("v_cvt_pk_bf16_f32 %0, %1, %2" : "=v"(P0.u[j]) : "v"(p[2*j]),   "v"(p[2*j+1]));
      asm("v_cvt_pk_bf16_f32 %0, %1, %2" : "=v"(P1.u[j]) : "v"(p[8+2*j]), "v"(p[8+2*j+1]));
    }
    #pragma unroll
    for(int f=0; f<4; f++){
      int row = f*16 + lr;
      short8 va  = *(const short8*)&Vb[(row*8 + (lh ^ swz))*8];
      short8 vb2 = *(const short8*)&Vb[(row*8 + ((4+lh) ^ swz))*8];
      o[f] = __builtin_amdgcn_mfma_f32_16x16x32_bf16(va,  P0.s8, o[f], 0,0,0);
      o[f] = __builtin_amdgcn_mfma_f32_16x16x32_bf16(vb2, P1.s8, o[f], 0,0,0);
    }
  };

  STAGE(0, 0);
  __syncthreads();
  int cur = 0;

  for(int t = 0; t < T-1; t++){
    STAGE(t+1, cur^1);
    body(t*64, Ks[cur], Vs[cur], false);
    __syncthreads();
    cur ^= 1;
  }
  body((T-1)*64, Ks[cur], Vs[cur], true);
  #undef STAGE

  ls += __shfl_xor(ls, 16, 64);
  ls += __shfl_xor(ls, 32, 64);

  const int b = bh >> 4, h = bh & 15;
  const float inv = 1.0f/ls;
  #pragma unroll
  for(int f=0; f<4; f++){
    u16x4 ov;
    #pragma unroll
    for(int t2=0;t2<4;t2++) ov[t2] = f2bf(o[f][t2]*inv);
    *(u16x4*)&O[(size_t)(b*SEQ + qg)*EMB + h*HD + f*16 + lh*4] = ov;
  }
}

extern "C" void kernel_launch(void* const* d_in, const int* in_sizes, int n_in,
                              void* d_out, int out_size, void* d_ws, size_t ws_size,
                              hipStream_t stream) {
  const float* emb   = (const float*)d_in[0];
  const float* cosb  = (const float*)d_in[1];
  const float* sinb  = (const float*)d_in[2];
  const float* nw    = (const float*)d_in[3];
  const float* qkvw  = (const float*)d_in[4];
  const float* outw  = (const float*)d_in[5];
  float* out = (float*)d_out;

  unsigned short* ws = (unsigned short*)d_ws;
  unsigned short* qkvWb = ws;                                  // 3072*1024
  unsigned short* outWb = qkvWb + (size_t)QKVN*EMB;            // 1024*1024
  unsigned short* normed = outWb + (size_t)EMB*EMB;            // 4096*1024
  unsigned short* attnout = normed;                            // alias (normed dead post-QKV)
  unsigned short* qb = normed + (size_t)BSROWS*EMB;            // 2*16*2048*64 each
  unsigned short* kb = qb + (size_t)NB*NH*SEQ*HD;
  unsigned short* vtb = kb + (size_t)NB*NH*SEQ*HD;

  const int prep_blocks = BSROWS + (QKVN*EMB/4 + EMB*EMB/4)/256;   // 8192
  k_prep<<<dim3(prep_blocks), dim3(256), 0, stream>>>(emb, nw, normed, qkvw, outw, qkvWb, outWb);
  // QKV: q/k columns (0..2047) with fused RoPE epilogue
  k_gemm<2><<<dim3(16, BSROWS/128), dim3(256), 0, stream>>>(
      normed, qkvWb, nullptr, nullptr, cosb, sinb, qb, kb, nullptr, BSROWS, QKVN, EMB, 0);
  // QKV: v columns (2048..3071) with fused transpose+perm epilogue
  k_gemm<3><<<dim3(8, BSROWS/128), dim3(256), 0, stream>>>(
      normed, qkvWb, nullptr, nullptr, nullptr, nullptr, nullptr, nullptr, vtb, BSROWS, QKVN, EMB, 2048);
  k_attn<<<dim3(SEQ/64 * NB*NH), dim3(256), 0, stream>>>(qb, kb, vtb, attnout);
  k_gemm<1><<<dim3(EMB/128, BSROWS/128), dim3(256), 0, stream>>>(
      attnout, outWb, out, emb, nullptr, nullptr, nullptr, nullptr, nullptr, BSROWS, EMB, EMB, 0);
}

// Round 10
// 191.962 us; speedup vs baseline: 1.1102x; 1.1102x over previous
//
#include <hip/hip_runtime.h>
#include <hip/hip_bf16.h>
#include <stdint.h>

#define EMB 1024
#define SEQ 2048
#define NB 2
#define NH 16
#define HD 64
#define QKVN 3072
#define BSROWS (NB*SEQ)   // 4096

typedef __attribute__((ext_vector_type(8))) short short8;
typedef __attribute__((ext_vector_type(4))) float f32x4;
typedef __attribute__((ext_vector_type(4))) unsigned short u16x4;

__device__ __forceinline__ float bf2f(unsigned short u){
  union{uint32_t i; float f;} x; x.i = ((uint32_t)u)<<16; return x.f;
}
__device__ __forceinline__ unsigned short f2bf(float f){
  union{float f; uint32_t i;} x; x.f = f;
  return (unsigned short)((x.i + 0x7FFFu + ((x.i>>16)&1u))>>16);
}

__device__ __forceinline__ void gload_lds16(const void* g, void* l){
  __builtin_amdgcn_global_load_lds((const __attribute__((address_space(1))) void*)g,
                                   (__attribute__((address_space(3))) void*)l, 16, 0, 0);
}

// ---------------- RMSNorm: one block per row, 256 thr, 4 f32/thr ----------------
__global__ __launch_bounds__(256) void k_rmsnorm(const float* __restrict__ x,
                                                 const float* __restrict__ w,
                                                 unsigned short* __restrict__ out){
  int row = blockIdx.x;
  const float4* xr = (const float4*)(x + (size_t)row*EMB);
  float4 v = xr[threadIdx.x];
  float ss = v.x*v.x + v.y*v.y + v.z*v.z + v.w*v.w;
  #pragma unroll
  for(int m=1;m<64;m<<=1) ss += __shfl_xor(ss, m, 64);
  __shared__ float red[4];
  if((threadIdx.x & 63)==0) red[threadIdx.x>>6] = ss;
  __syncthreads();
  float tot = red[0]+red[1]+red[2]+red[3];
  float rinv = rsqrtf(tot*(1.0f/EMB) + 1.1920929e-07f);
  float4 wv = ((const float4*)w)[threadIdx.x];
  u16x4 o;
  o.x = f2bf(v.x*wv.x*rinv); o.y = f2bf(v.y*wv.y*rinv);
  o.z = f2bf(v.z*wv.z*rinv); o.w = f2bf(v.w*wv.w*rinv);
  *(u16x4*)(out + (size_t)row*EMB + threadIdx.x*4) = o;
}

// ---------------- fp32 -> bf16 weight convert (both weights, one launch) ---------
__global__ __launch_bounds__(256) void k_f2bf2(const float* __restrict__ a,
                                               const float* __restrict__ b,
                                               unsigned short* __restrict__ oa,
                                               unsigned short* __restrict__ ob,
                                               int na4, int nb4){
  int i = blockIdx.x*256 + threadIdx.x;
  const float* src; unsigned short* dst; int idx;
  if(i < na4){ src = a; dst = oa; idx = i; }
  else { idx = i - na4; if(idx >= nb4) return; src = b; dst = ob; }
  float4 v = ((const float4*)src)[idx];
  u16x4 o;
  o.x = f2bf(v.x); o.y = f2bf(v.y); o.z = f2bf(v.z); o.w = f2bf(v.w);
  ((u16x4*)dst)[idx] = o;
}

// ---------------- GEMM: C[M,N] = A[M,K](bf16) @ W[N,K](bf16)^T ----------------
// 128x128 tile, BK=64 (half the barriers of BK=32), chunk-XOR swizzled LDS
// (same involution as k_attn staging: src chunk ^= r&7, read chunk ^(lr&7)).
// MODE 0: store bf16 to Cb.  MODE 1: store fp32 (acc + resid) to Cf.
template<int MODE>
__global__ __launch_bounds__(256) void k_gemm(const unsigned short* __restrict__ A,
                                              const unsigned short* __restrict__ W,
                                              unsigned short* __restrict__ Cb,
                                              float* __restrict__ Cf,
                                              const float* __restrict__ resid,
                                              int M, int N, int K){
  __shared__ unsigned short As[128*64];
  __shared__ unsigned short Bs[128*64];
  const int tid = threadIdx.x;
  const int l  = tid & 63;
  const int wid = tid >> 6;
  const int lr = l & 15, lh = l >> 4;
  const int m0 = blockIdx.y * 128, n0 = blockIdx.x * 128;
  const int wr = wid >> 1, wc = wid & 1;   // 2x2 waves of 64x64
  const int swz = lr & 7;

  f32x4 acc[4][4] = {};

  const int nk = K >> 6;
  for(int kt=0; kt<nk; kt++){
    const int k0 = kt*64;
    #pragma unroll
    for(int j=0;j<4;j++){
      int c = j*256 + tid;            // chunk 0..1023, 16B each (row r, col-chunk kc)
      int sb = j*256 + wid*64;        // wave-uniform LDS base chunk
      int r = c >> 3, kc = c & 7;
      gload_lds16(A + (size_t)(m0+r)*K + k0 + ((kc ^ (r & 7))*8), &As[(size_t)sb*8]);
      gload_lds16(W + (size_t)(n0+r)*K + k0 + ((kc ^ (r & 7))*8), &Bs[(size_t)sb*8]);
    }
    __syncthreads();
    #pragma unroll
    for(int kk=0; kk<2; kk++){
      short8 af[4], bfr[4];
      #pragma unroll
      for(int i=0;i<4;i++){
        int ra = wr*64 + i*16 + lr;
        int rb = wc*64 + i*16 + lr;
        af[i]  = *(const short8*)&As[(size_t)((ra*8 + ((kk*4+lh) ^ swz))*8)];
        bfr[i] = *(const short8*)&Bs[(size_t)((rb*8 + ((kk*4+lh) ^ swz))*8)];
      }
      #pragma unroll
      for(int i=0;i<4;i++)
        #pragma unroll
        for(int jn=0;jn<4;jn++)
          acc[i][jn] = __builtin_amdgcn_mfma_f32_16x16x32_bf16(af[i], bfr[jn], acc[i][jn], 0,0,0);
    }
    __syncthreads();
  }

  const int rbase = m0 + wr*64, cbase = n0 + wc*64;
  #pragma unroll
  for(int i=0;i<4;i++){
    #pragma unroll
    for(int jn=0;jn<4;jn++){
      int rr = rbase + i*16 + lh*4;
      int cc = cbase + jn*16 + lr;
      #pragma unroll
      for(int t=0;t<4;t++){
        float val = acc[i][jn][t];
        if(MODE==0){
          Cb[(size_t)(rr+t)*N + cc] = f2bf(val);
        } else {
          Cf[(size_t)(rr+t)*N + cc] = val + resid[(size_t)(rr+t)*N + cc];
        }
      }
    }
  }
}

// ---------------- RoPE + scatter q,k into [B,H,S,64] bf16 (vectorized pairs) --------
// Q additionally pre-scaled by 0.125*log2(e) so attn's QK^T lands in exp2 domain.
__global__ __launch_bounds__(256) void k_rope(const unsigned short* __restrict__ qkv,
                                              const float* __restrict__ cosb,
                                              const float* __restrict__ sinb,
                                              unsigned short* __restrict__ qb,
                                              unsigned short* __restrict__ kb){
  int t = blockIdx.x*256 + threadIdx.x;     // 0 .. 4096*2*16*8-1
  int g = t & 7;             // d-group: d0 = g*4
  int h = (t >> 3) & 15;
  int part = (t >> 7) & 1;   // 0=q, 1=k
  int r = t >> 8;            // 0..4095
  int b = r >> 11, s = r & 2047;
  const float qs = part ? 1.0f : 0.125f*1.4426950408889634f;
  const unsigned short* src = qkv + (size_t)r*QKVN + part*1024 + h*64 + g*4;
  u16x4 xl = *(const u16x4*)src;
  u16x4 xh = *(const u16x4*)(src + 32);
  f32x4 cl = *(const f32x4*)(cosb + s*64 + g*4);
  f32x4 ch = *(const f32x4*)(cosb + s*64 + 32 + g*4);
  f32x4 sl = *(const f32x4*)(sinb + s*64 + g*4);
  f32x4 sh = *(const f32x4*)(sinb + s*64 + 32 + g*4);
  u16x4 lo, hi;
  #pragma unroll
  for(int j=0;j<4;j++){
    float a = bf2f(xl[j]), bb = bf2f(xh[j]);
    lo[j] = f2bf((cl[j]*a  + sl[j]*bb)*qs);
    hi[j] = f2bf((ch[j]*bb + sh[j]*a)*qs);
  }
  unsigned short* dst = (part ? kb : qb) + ((size_t)((b*NH + h)*SEQ + s))*HD + g*4;
  *(u16x4*)dst = lo;
  *(u16x4*)(dst + 32) = hi;
}

// ---------------- V transpose with PV k-permutation: qkv v-part -> Vt2[B,H,64,S] ----
__global__ __launch_bounds__(256) void k_vt(const unsigned short* __restrict__ qkv,
                                            unsigned short* __restrict__ vt){
  __shared__ unsigned short t[64][65];
  int bh = blockIdx.y;                 // 0..31
  int b = bh >> 4, h = bh & 15;
  int s0 = blockIdx.x*64;
  int tid = threadIdx.x;
  #pragma unroll
  for(int it=0; it<4; it++){
    int idx = it*256 + tid;            // 0..1023, 4 ushorts each
    int si = idx >> 4;
    int dj = (idx & 15)*4;
    const unsigned short* g = qkv + (size_t)(b*SEQ + s0 + si)*QKVN + 2048 + h*64 + dj;
    u16x4 v = *(const u16x4*)g;
    t[dj+0][si] = v.x; t[dj+1][si] = v.y; t[dj+2][si] = v.z; t[dj+3][si] = v.w;
  }
  __syncthreads();
  int d = tid >> 2, sc = (tid & 3)*16;
  unsigned short* out = vt + (size_t)(bh*64 + d)*SEQ + s0 + sc;
  #pragma unroll
  for(int u=0;u<4;u++){
    u16x4 o;
    #pragma unroll
    for(int e=0;e<4;e++){
      int n = sc + u*4 + e;            // position within 64 cols
      int blk32 = n >> 5, n32 = n & 31;
      int nc = n32 >> 2, e4 = n32 & 3;
      int oc = (nc & 1) ? (4 + (nc >> 1)) : (nc >> 1);
      o[e] = t[d][blk32*32 + oc*4 + e4];
    }
    *(u16x4*)(out + u*4) = o;
  }
}

// ---------------- Flash attention: LDS-staged KV64, lean softmax -------------------
__global__ __launch_bounds__(256, 4) void k_attn(const unsigned short* __restrict__ Q,
                                                 const unsigned short* __restrict__ K,
                                                 const unsigned short* __restrict__ Vt,
                                                 unsigned short* __restrict__ O){
  __shared__ unsigned short Ks[2][64*64];
  __shared__ unsigned short Vs[2][64*64];
  const int tid = threadIdx.x;
  const int l = tid & 63, wid = tid >> 6;
  const int lr = l & 15, lh = l >> 4;
  const int id = blockIdx.x;
  const int slot = id >> 3;
  const int bh  = (id & 7)*4 + (slot & 3);    // XCD-local bh group (K+V = 2MB/XCD L2)
  const int qblk = 31 - (slot >> 2);          // heavy q-blocks dispatch first
  const int q0 = qblk*64 + wid*16;
  const unsigned short* Qp = Q + ((size_t)bh*SEQ + q0)*HD;
  const unsigned short* Kp = K + (size_t)bh*SEQ*HD;
  const unsigned short* Vp = Vt + (size_t)bh*HD*SEQ;

  short8 qf0 = *(const short8*)&Qp[lr*HD + lh*8];
  short8 qf1 = *(const short8*)&Qp[lr*HD + 32 + lh*8];

  f32x4 o[4] = {};
  float m_ = -__builtin_inff();
  float ls = 0.f;                 // per-lane; reduced once at the end
  const int qg = q0 + lr;
  const int swz = lr & 7;
  const int T = qblk + 1;

  #define STAGE(t_, b_) { \
    const int kv0s = (t_)*64; \
    _Pragma("unroll") \
    for(int j=0;j<2;j++){ \
      int s = j*256 + tid; \
      int sb = j*256 + wid*64; \
      int r = s >> 3, c = s & 7; \
      gload_lds16(Kp + (size_t)(kv0s + r)*HD + ((c ^ (r & 7))*8), &Ks[b_][sb*8]); \
      gload_lds16(Vp + (size_t)r*SEQ + kv0s + ((c ^ (r & 7))*8), &Vs[b_][sb*8]); \
    } }

  auto body = [&](int kv0, const unsigned short* Kb, const unsigned short* Vb,
                  bool masked){
    f32x4 s4[4] = {};
    #pragma unroll
    for(int i=0;i<4;i++){
      int row = i*16 + lr;
      short8 ka = *(const short8*)&Kb[(row*8 + (lh ^ swz))*8];
      short8 kc = *(const short8*)&Kb[(row*8 + ((4+lh) ^ swz))*8];
      s4[i] = __builtin_amdgcn_mfma_f32_16x16x32_bf16(ka, qf0, s4[i], 0,0,0);
      s4[i] = __builtin_amdgcn_mfma_f32_16x16x32_bf16(kc, qf1, s4[i], 0,0,0);
    }
    float v[16];
    #pragma unroll
    for(int i=0;i<4;i++)
      #pragma unroll
      for(int j=0;j<4;j++){
        float val = s4[i][j];
        if(masked){
          int kvg = kv0 + i*16 + lh*4 + j;
          val = (kvg <= qg) ? val : -__builtin_inff();
        }
        v[i*4+j] = val;
      }
    float pm = v[0];
    #pragma unroll
    for(int j=1;j<16;j++) pm = fmaxf(pm, v[j]);
    if(__any(pm > m_ + 11.544f)){
      float mx = fmaxf(pm, __shfl_xor(pm, 16, 64));
      mx = fmaxf(mx, __shfl_xor(mx, 32, 64));
      float mn = fmaxf(m_, mx);
      float cr = __builtin_amdgcn_exp2f(m_ - mn);
      m_ = mn;
      ls *= cr;
      #pragma unroll
      for(int f=0; f<4; f++) o[f] *= cr;
    }
    float p[16], rs = 0.f;
    #pragma unroll
    for(int j=0;j<16;j++){ p[j] = __builtin_amdgcn_exp2f(v[j] - m_); rs += p[j]; }
    ls += rs;

    union { short8 s8; uint32_t u[4]; } P0, P1;
    #pragma unroll
    for(int j=0;j<4;j++){
      asm("v_cvt_pk_bf16_f32 %0, %1, %2" : "=v"(P0.u[j]) : "v"(p[2*j]),   "v"(p[2*j+1]));
      asm("v_cvt_pk_bf16_f32 %0, %1, %2" : "=v"(P1.u[j]) : "v"(p[8+2*j]), "v"(p[8+2*j+1]));
    }
    #pragma unroll
    for(int f=0; f<4; f++){
      int row = f*16 + lr;
      short8 va  = *(const short8*)&Vb[(row*8 + (lh ^ swz))*8];
      short8 vb2 = *(const short8*)&Vb[(row*8 + ((4+lh) ^ swz))*8];
      o[f] = __builtin_amdgcn_mfma_f32_16x16x32_bf16(va,  P0.s8, o[f], 0,0,0);
      o[f] = __builtin_amdgcn_mfma_f32_16x16x32_bf16(vb2, P1.s8, o[f], 0,0,0);
    }
  };

  STAGE(0, 0);
  __syncthreads();
  int cur = 0;

  for(int t = 0; t < T-1; t++){
    STAGE(t+1, cur^1);
    body(t*64, Ks[cur], Vs[cur], false);
    __syncthreads();
    cur ^= 1;
  }
  body((T-1)*64, Ks[cur], Vs[cur], true);
  #undef STAGE

  ls += __shfl_xor(ls, 16, 64);
  ls += __shfl_xor(ls, 32, 64);

  const int b = bh >> 4, h = bh & 15;
  const float inv = 1.0f/ls;
  #pragma unroll
  for(int f=0; f<4; f++){
    u16x4 ov;
    #pragma unroll
    for(int t2=0;t2<4;t2++) ov[t2] = f2bf(o[f][t2]*inv);
    *(u16x4*)&O[(size_t)(b*SEQ + qg)*EMB + h*HD + f*16 + lh*4] = ov;
  }
}

extern "C" void kernel_launch(void* const* d_in, const int* in_sizes, int n_in,
                              void* d_out, int out_size, void* d_ws, size_t ws_size,
                              hipStream_t stream) {
  const float* emb   = (const float*)d_in[0];
  const float* cosb  = (const float*)d_in[1];
  const float* sinb  = (const float*)d_in[2];
  const float* nw    = (const float*)d_in[3];
  const float* qkvw  = (const float*)d_in[4];
  const float* outw  = (const float*)d_in[5];
  float* out = (float*)d_out;

  unsigned short* ws = (unsigned short*)d_ws;
  unsigned short* qkvWb = ws;                                  // 3072*1024
  unsigned short* outWb = qkvWb + (size_t)QKVN*EMB;            // 1024*1024
  unsigned short* normed = outWb + (size_t)EMB*EMB;            // 4096*1024
  unsigned short* attnout = normed;                            // alias (normed dead post-QKV GEMM)
  unsigned short* qkvb = normed + (size_t)BSROWS*EMB;          // 4096*3072
  unsigned short* qb = qkvb + (size_t)BSROWS*QKVN;             // 2*16*2048*64
  unsigned short* kb = qb + (size_t)NB*NH*SEQ*HD;
  unsigned short* vtb = kb + (size_t)NB*NH*SEQ*HD;

  const int na4 = QKVN*EMB/4, nb4 = EMB*EMB/4;
  k_rmsnorm<<<dim3(BSROWS), dim3(256), 0, stream>>>(emb, nw, normed);
  k_f2bf2<<<dim3((na4+nb4+255)/256), dim3(256), 0, stream>>>(qkvw, outw, qkvWb, outWb, na4, nb4);
  k_gemm<0><<<dim3(QKVN/128, BSROWS/128), dim3(256), 0, stream>>>(
      normed, qkvWb, qkvb, nullptr, nullptr, BSROWS, QKVN, EMB);
  k_rope<<<dim3(BSROWS, 1), dim3(256), 0, stream>>>(qkvb, cosb, sinb, qb, kb);
  k_vt<<<dim3(SEQ/64, NB*NH), dim3(256), 0, stream>>>(qkvb, vtb);
  k_attn<<<dim3(SEQ/64 * NB*NH), dim3(256), 0, stream>>>(qb, kb, vtb, attnout);
  k_gemm<1><<<dim3(EMB/128, BSROWS/128), dim3(256), 0, stream>>>(
      attnout, outWb, nullptr, out, emb, BSROWS, EMB, EMB);
}

// Round 12
// 188.819 us; speedup vs baseline: 1.1287x; 1.0166x over previous
//
#include <hip/hip_runtime.h>
#include <hip/hip_bf16.h>
#include <stdint.h>

#define EMB 1024
#define SEQ 2048
#define NB 2
#define NH 16
#define HD 64
#define QKVN 3072
#define BSROWS (NB*SEQ)   // 4096

typedef __attribute__((ext_vector_type(8))) short short8;
typedef __attribute__((ext_vector_type(4))) float f32x4;
typedef __attribute__((ext_vector_type(4))) unsigned short u16x4;

__device__ __forceinline__ float bf2f(unsigned short u){
  union{uint32_t i; float f;} x; x.i = ((uint32_t)u)<<16; return x.f;
}
__device__ __forceinline__ unsigned short f2bf(float f){
  union{float f; uint32_t i;} x; x.f = f;
  return (unsigned short)((x.i + 0x7FFFu + ((x.i>>16)&1u))>>16);
}

__device__ __forceinline__ void gload_lds16(const void* g, void* l){
  __builtin_amdgcn_global_load_lds((const __attribute__((address_space(1))) void*)g,
                                   (__attribute__((address_space(3))) void*)l, 16, 0, 0);
}

// ---------------- RMSNorm: one block per row, 256 thr, 4 f32/thr ----------------
__global__ __launch_bounds__(256) void k_rmsnorm(const float* __restrict__ x,
                                                 const float* __restrict__ w,
                                                 unsigned short* __restrict__ out){
  int row = blockIdx.x;
  const float4* xr = (const float4*)(x + (size_t)row*EMB);
  float4 v = xr[threadIdx.x];
  float ss = v.x*v.x + v.y*v.y + v.z*v.z + v.w*v.w;
  #pragma unroll
  for(int m=1;m<64;m<<=1) ss += __shfl_xor(ss, m, 64);
  __shared__ float red[4];
  if((threadIdx.x & 63)==0) red[threadIdx.x>>6] = ss;
  __syncthreads();
  float tot = red[0]+red[1]+red[2]+red[3];
  float rinv = rsqrtf(tot*(1.0f/EMB) + 1.1920929e-07f);
  float4 wv = ((const float4*)w)[threadIdx.x];
  u16x4 o;
  o.x = f2bf(v.x*wv.x*rinv); o.y = f2bf(v.y*wv.y*rinv);
  o.z = f2bf(v.z*wv.z*rinv); o.w = f2bf(v.w*wv.w*rinv);
  *(u16x4*)(out + (size_t)row*EMB + threadIdx.x*4) = o;
}

// ---------------- fp32 -> bf16 weight convert (both weights, one launch) ---------
__global__ __launch_bounds__(256) void k_f2bf2(const float* __restrict__ a,
                                               const float* __restrict__ b,
                                               unsigned short* __restrict__ oa,
                                               unsigned short* __restrict__ ob,
                                               int na4, int nb4){
  int i = blockIdx.x*256 + threadIdx.x;
  const float* src; unsigned short* dst; int idx;
  if(i < na4){ src = a; dst = oa; idx = i; }
  else { idx = i - na4; if(idx >= nb4) return; src = b; dst = ob; }
  float4 v = ((const float4*)src)[idx];
  u16x4 o;
  o.x = f2bf(v.x); o.y = f2bf(v.y); o.z = f2bf(v.z); o.w = f2bf(v.w);
  ((u16x4*)dst)[idx] = o;
}

// ---------------- GEMM: C[M,N] = A[M,K](bf16) @ W[N,K](bf16)^T ----------------
// 128x128 tile, BK=64, chunk-XOR swizzled LDS (both-sides involution).
template<int MODE>
__global__ __launch_bounds__(256) void k_gemm(const unsigned short* __restrict__ A,
                                              const unsigned short* __restrict__ W,
                                              unsigned short* __restrict__ Cb,
                                              float* __restrict__ Cf,
                                              const float* __restrict__ resid,
                                              int M, int N, int K){
  __shared__ unsigned short As[128*64];
  __shared__ unsigned short Bs[128*64];
  const int tid = threadIdx.x;
  const int l  = tid & 63;
  const int wid = tid >> 6;
  const int lr = l & 15, lh = l >> 4;
  const int m0 = blockIdx.y * 128, n0 = blockIdx.x * 128;
  const int wr = wid >> 1, wc = wid & 1;   // 2x2 waves of 64x64
  const int swz = lr & 7;

  f32x4 acc[4][4] = {};

  const int nk = K >> 6;
  for(int kt=0; kt<nk; kt++){
    const int k0 = kt*64;
    #pragma unroll
    for(int j=0;j<4;j++){
      int c = j*256 + tid;            // chunk 0..1023, 16B each (row r, col-chunk kc)
      int sb = j*256 + wid*64;        // wave-uniform LDS base chunk
      int r = c >> 3, kc = c & 7;
      gload_lds16(A + (size_t)(m0+r)*K + k0 + ((kc ^ (r & 7))*8), &As[(size_t)sb*8]);
      gload_lds16(W + (size_t)(n0+r)*K + k0 + ((kc ^ (r & 7))*8), &Bs[(size_t)sb*8]);
    }
    __syncthreads();
    #pragma unroll
    for(int kk=0; kk<2; kk++){
      short8 af[4], bfr[4];
      #pragma unroll
      for(int i=0;i<4;i++){
        int ra = wr*64 + i*16 + lr;
        int rb = wc*64 + i*16 + lr;
        af[i]  = *(const short8*)&As[(size_t)((ra*8 + ((kk*4+lh) ^ swz))*8)];
        bfr[i] = *(const short8*)&Bs[(size_t)((rb*8 + ((kk*4+lh) ^ swz))*8)];
      }
      #pragma unroll
      for(int i=0;i<4;i++)
        #pragma unroll
        for(int jn=0;jn<4;jn++)
          acc[i][jn] = __builtin_amdgcn_mfma_f32_16x16x32_bf16(af[i], bfr[jn], acc[i][jn], 0,0,0);
    }
    __syncthreads();
  }

  const int rbase = m0 + wr*64, cbase = n0 + wc*64;
  #pragma unroll
  for(int i=0;i<4;i++){
    #pragma unroll
    for(int jn=0;jn<4;jn++){
      int rr = rbase + i*16 + lh*4;
      int cc = cbase + jn*16 + lr;
      #pragma unroll
      for(int t=0;t<4;t++){
        float val = acc[i][jn][t];
        if(MODE==0){
          Cb[(size_t)(rr+t)*N + cc] = f2bf(val);
        } else {
          Cf[(size_t)(rr+t)*N + cc] = val + resid[(size_t)(rr+t)*N + cc];
        }
      }
    }
  }
}

// ---------------- RoPE + scatter q,k into [B,H,S,64] bf16 (vectorized pairs) --------
// Q additionally pre-scaled by 0.125*log2(e) so attn's QK^T lands in exp2 domain.
__global__ __launch_bounds__(256) void k_rope(const unsigned short* __restrict__ qkv,
                                              const float* __restrict__ cosb,
                                              const float* __restrict__ sinb,
                                              unsigned short* __restrict__ qb,
                                              unsigned short* __restrict__ kb){
  int t = blockIdx.x*256 + threadIdx.x;     // 0 .. 4096*2*16*8-1
  int g = t & 7;             // d-group: d0 = g*4
  int h = (t >> 3) & 15;
  int part = (t >> 7) & 1;   // 0=q, 1=k
  int r = t >> 8;            // 0..4095
  int b = r >> 11, s = r & 2047;
  const float qs = part ? 1.0f : 0.125f*1.4426950408889634f;
  const unsigned short* src = qkv + (size_t)r*QKVN + part*1024 + h*64 + g*4;
  u16x4 xl = *(const u16x4*)src;
  u16x4 xh = *(const u16x4*)(src + 32);
  f32x4 cl = *(const f32x4*)(cosb + s*64 + g*4);
  f32x4 ch = *(const f32x4*)(cosb + s*64 + 32 + g*4);
  f32x4 sl = *(const f32x4*)(sinb + s*64 + g*4);
  f32x4 sh = *(const f32x4*)(sinb + s*64 + 32 + g*4);
  u16x4 lo, hi;
  #pragma unroll
  for(int j=0;j<4;j++){
    float a = bf2f(xl[j]), bb = bf2f(xh[j]);
    lo[j] = f2bf((cl[j]*a  + sl[j]*bb)*qs);
    hi[j] = f2bf((ch[j]*bb + sh[j]*a)*qs);
  }
  unsigned short* dst = (part ? kb : qb) + ((size_t)((b*NH + h)*SEQ + s))*HD + g*4;
  *(u16x4*)dst = lo;
  *(u16x4*)(dst + 32) = hi;
}

// ---------------- V transpose with PV k-permutation: qkv v-part -> Vt2[B,H,64,S] ----
__global__ __launch_bounds__(256) void k_vt(const unsigned short* __restrict__ qkv,
                                            unsigned short* __restrict__ vt){
  __shared__ unsigned short t[64][65];
  int bh = blockIdx.y;                 // 0..31
  int b = bh >> 4, h = bh & 15;
  int s0 = blockIdx.x*64;
  int tid = threadIdx.x;
  #pragma unroll
  for(int it=0; it<4; it++){
    int idx = it*256 + tid;            // 0..1023, 4 ushorts each
    int si = idx >> 4;
    int dj = (idx & 15)*4;
    const unsigned short* g = qkv + (size_t)(b*SEQ + s0 + si)*QKVN + 2048 + h*64 + dj;
    u16x4 v = *(const u16x4*)g;
    t[dj+0][si] = v.x; t[dj+1][si] = v.y; t[dj+2][si] = v.z; t[dj+3][si] = v.w;
  }
  __syncthreads();
  int d = tid >> 2, sc = (tid & 3)*16;
  unsigned short* out = vt + (size_t)(bh*64 + d)*SEQ + s0 + sc;
  #pragma unroll
  for(int u=0;u<4;u++){
    u16x4 o;
    #pragma unroll
    for(int e=0;e<4;e++){
      int n = sc + u*4 + e;            // position within 64 cols
      int blk32 = n >> 5, n32 = n & 31;
      int nc = n32 >> 2, e4 = n32 & 3;
      int oc = (nc & 1) ? (4 + (nc >> 1)) : (nc >> 1);
      o[e] = t[d][blk32*32 + oc*4 + e4];
    }
    *(u16x4*)(out + u*4) = o;
  }
}

// ---------------- Flash attention: 2-pass balanced (tiles 31-p then p) -------------
// 512 blocks. Each pass is the proven single-tile pipeline (R10) verbatim; pass 0
// runs the heavy Q-tile 31-p, pass 1 the light Q-tile p. Work/block = const 33.
// __syncthreads between passes protects LDS reuse.
__global__ __launch_bounds__(256, 4) void k_attn(const unsigned short* __restrict__ Q,
                                                 const unsigned short* __restrict__ K,
                                                 const unsigned short* __restrict__ Vt,
                                                 unsigned short* __restrict__ O){
  __shared__ unsigned short Ks[2][64*64];
  __shared__ unsigned short Vs[2][64*64];
  const int tid = threadIdx.x;
  const int l = tid & 63, wid = tid >> 6;
  const int lr = l & 15, lh = l >> 4;
  const int id = blockIdx.x;
  const int bh = (id & 7)*4 + ((id >> 3) & 3);  // XCD-local bh group
  const int p  = id >> 5;                       // 0..15
  const unsigned short* Kp = K + (size_t)bh*SEQ*HD;
  const unsigned short* Vp = Vt + (size_t)bh*HD*SEQ;
  const int b = bh >> 4, h = bh & 15;
  const int swz = lr & 7;

  #define STAGE(t_, b_) { \
    const int kv0s = (t_)*64; \
    _Pragma("unroll") \
    for(int j=0;j<2;j++){ \
      int s = j*256 + tid; \
      int sb = j*256 + wid*64; \
      int r = s >> 3, c = s & 7; \
      gload_lds16(Kp + (size_t)(kv0s + r)*HD + ((c ^ (r & 7))*8), &Ks[b_][sb*8]); \
      gload_lds16(Vp + (size_t)r*SEQ + kv0s + ((c ^ (r & 7))*8), &Vs[b_][sb*8]); \
    } }

  for(int pass = 0; pass < 2; pass++){
    const int qblk = pass ? p : (31 - p);
    const int q0 = qblk*64 + wid*16;
    const unsigned short* Qp = Q + ((size_t)bh*SEQ + q0)*HD;

    short8 qf0 = *(const short8*)&Qp[lr*HD + lh*8];
    short8 qf1 = *(const short8*)&Qp[lr*HD + 32 + lh*8];

    f32x4 o[4] = {};
    float m_ = -__builtin_inff();
    float ls = 0.f;
    const int qg = q0 + lr;
    const int T = qblk + 1;

    auto body = [&](int kv0, const unsigned short* Kb, const unsigned short* Vb,
                    bool masked){
      f32x4 s4[4] = {};
      #pragma unroll
      for(int i=0;i<4;i++){
        int row = i*16 + lr;
        short8 ka = *(const short8*)&Kb[(row*8 + (lh ^ swz))*8];
        short8 kc = *(const short8*)&Kb[(row*8 + ((4+lh) ^ swz))*8];
        s4[i] = __builtin_amdgcn_mfma_f32_16x16x32_bf16(ka, qf0, s4[i], 0,0,0);
        s4[i] = __builtin_amdgcn_mfma_f32_16x16x32_bf16(kc, qf1, s4[i], 0,0,0);
      }
      float v[16];
      #pragma unroll
      for(int i=0;i<4;i++)
        #pragma unroll
        for(int j=0;j<4;j++){
          float val = s4[i][j];
          if(masked){
            int kvg = kv0 + i*16 + lh*4 + j;
            val = (kvg <= qg) ? val : -__builtin_inff();
          }
          v[i*4+j] = val;
        }
      float pm = v[0];
      #pragma unroll
      for(int j=1;j<16;j++) pm = fmaxf(pm, v[j]);
      if(__any(pm > m_ + 11.544f)){
        float mx = fmaxf(pm, __shfl_xor(pm, 16, 64));
        mx = fmaxf(mx, __shfl_xor(mx, 32, 64));
        float mn = fmaxf(m_, mx);
        float cr = __builtin_amdgcn_exp2f(m_ - mn);
        m_ = mn;
        ls *= cr;
        #pragma unroll
        for(int f=0; f<4; f++) o[f] *= cr;
      }
      float pp[16], rs = 0.f;
      #pragma unroll
      for(int j=0;j<16;j++){ pp[j] = __builtin_amdgcn_exp2f(v[j] - m_); rs += pp[j]; }
      ls += rs;

      union { short8 s8; uint32_t u[4]; } P0, P1;
      #pragma unroll
      for(int j=0;j<4;j++){
        asm("v_cvt_pk_bf16_f32 %0, %1, %2" : "=v"(P0.u[j]) : "v"(pp[2*j]),   "v"(pp[2*j+1]));
        asm("v_cvt_pk_bf16_f32 %0, %1, %2" : "=v"(P1.u[j]) : "v"(pp[8+2*j]), "v"(pp[8+2*j+1]));
      }
      #pragma unroll
      for(int f=0; f<4; f++){
        int row = f*16 + lr;
        short8 va  = *(const short8*)&Vb[(row*8 + (lh ^ swz))*8];
        short8 vb2 = *(const short8*)&Vb[(row*8 + ((4+lh) ^ swz))*8];
        o[f] = __builtin_amdgcn_mfma_f32_16x16x32_bf16(va,  P0.s8, o[f], 0,0,0);
        o[f] = __builtin_amdgcn_mfma_f32_16x16x32_bf16(vb2, P1.s8, o[f], 0,0,0);
      }
    };

    STAGE(0, 0);
    __syncthreads();
    int cur = 0;

    for(int t = 0; t < T-1; t++){
      STAGE(t+1, cur^1);
      body(t*64, Ks[cur], Vs[cur], false);
      __syncthreads();
      cur ^= 1;
    }
    body((T-1)*64, Ks[cur], Vs[cur], true);

    ls += __shfl_xor(ls, 16, 64);
    ls += __shfl_xor(ls, 32, 64);

    const float inv = 1.0f/ls;
    #pragma unroll
    for(int f=0; f<4; f++){
      u16x4 ov;
      #pragma unroll
      for(int t2=0;t2<4;t2++) ov[t2] = f2bf(o[f][t2]*inv);
      *(u16x4*)&O[(size_t)(b*SEQ + qg)*EMB + h*HD + f*16 + lh*4] = ov;
    }
    __syncthreads();   // all LDS reads of this pass done before next pass stages
  }
  #undef STAGE
}

extern "C" void kernel_launch(void* const* d_in, const int* in_sizes, int n_in,
                              void* d_out, int out_size, void* d_ws, size_t ws_size,
                              hipStream_t stream) {
  const float* emb   = (const float*)d_in[0];
  const float* cosb  = (const float*)d_in[1];
  const float* sinb  = (const float*)d_in[2];
  const float* nw    = (const float*)d_in[3];
  const float* qkvw  = (const float*)d_in[4];
  const float* outw  = (const float*)d_in[5];
  float* out = (float*)d_out;

  unsigned short* ws = (unsigned short*)d_ws;
  unsigned short* qkvWb = ws;                                  // 3072*1024
  unsigned short* outWb = qkvWb + (size_t)QKVN*EMB;            // 1024*1024
  unsigned short* normed = outWb + (size_t)EMB*EMB;            // 4096*1024
  unsigned short* attnout = normed;                            // alias (normed dead post-QKV GEMM)
  unsigned short* qkvb = normed + (size_t)BSROWS*EMB;          // 4096*3072
  unsigned short* qb = qkvb + (size_t)BSROWS*QKVN;             // 2*16*2048*64
  unsigned short* kb = qb + (size_t)NB*NH*SEQ*HD;
  unsigned short* vtb = kb + (size_t)NB*NH*SEQ*HD;

  const int na4 = QKVN*EMB/4, nb4 = EMB*EMB/4;
  k_rmsnorm<<<dim3(BSROWS), dim3(256), 0, stream>>>(emb, nw, normed);
  k_f2bf2<<<dim3((na4+nb4+255)/256), dim3(256), 0, stream>>>(qkvw, outw, qkvWb, outWb, na4, nb4);
  k_gemm<0><<<dim3(QKVN/128, BSROWS/128), dim3(256), 0, stream>>>(
      normed, qkvWb, qkvb, nullptr, nullptr, BSROWS, QKVN, EMB);
  k_rope<<<dim3(BSROWS, 1), dim3(256), 0, stream>>>(qkvb, cosb, sinb, qb, kb);
  k_vt<<<dim3(SEQ/64, NB*NH), dim3(256), 0, stream>>>(qkvb, vtb);
  k_attn<<<dim3(512), dim3(256), 0, stream>>>(qb, kb, vtb, attnout);
  k_gemm<1><<<dim3(EMB/128, BSROWS/128), dim3(256), 0, stream>>>(
      attnout, outWb, nullptr, out, emb, BSROWS, EMB, EMB);
}